// Round 9
// baseline (1895.865 us; speedup 1.0000x reference)
//
#include <hip/hip_runtime.h>

#define D 128
#define SCAN_CH 1024
#define SA_STRIDE 136   // fp16 units; 272B row
#define SC_STRIDE 132   // fp32 units; 528B row
#define NPB 64          // nodes per conv block
#define CONV_THREADS 512

typedef _Float16 f16x8 __attribute__((ext_vector_type(8)));
typedef _Float16 f16x4 __attribute__((ext_vector_type(4)));
typedef float f32x4 __attribute__((ext_vector_type(4)));

// ---------------- CSR build (XCD-affinity: blockIdx%8 owns dst-range) ----------------

__global__ void hist_kernel(const int* __restrict__ dst, int* __restrict__ counts,
                            int E, int N) {
  int range = blockIdx.x & 7;
  int lo = (int)(((long long)N * range) >> 3);
  int hi = (int)(((long long)N * (range + 1)) >> 3);
  int stride = (gridDim.x >> 3) * blockDim.x;
  for (int e = (blockIdx.x >> 3) * blockDim.x + threadIdx.x; e < E; e += stride) {
    int d = dst[e];
    if (d >= lo && d < hi) atomicAdd(&counts[d], 1);
  }
}

__global__ void fill_kernel(const int* __restrict__ src, const int* __restrict__ dst,
    int* __restrict__ fillp, int* __restrict__ csr_src, int E, int N) {
  int range = blockIdx.x & 7;
  int lo = (int)(((long long)N * range) >> 3);
  int hi = (int)(((long long)N * (range + 1)) >> 3);
  int stride = (gridDim.x >> 3) * blockDim.x;
  for (int e = (blockIdx.x >> 3) * blockDim.x + threadIdx.x; e < E; e += stride) {
    int d = dst[e];
    if (d >= lo && d < hi) {
      int s = src[e];
      int p = atomicAdd(&fillp[d], 1);
      csr_src[p] = s;
    }
  }
}

// dnr[n] = (dn = 1/sqrt(deg+1), rdn = sqrt(deg+1))
__global__ void dis_kernel(const int* __restrict__ counts, float2* __restrict__ dnr, int N) {
  int n = blockIdx.x * blockDim.x + threadIdx.x;
  if (n < N) {
    float c = (float)counts[n] + 1.0f;
    dnr[n] = make_float2(rsqrtf(c), sqrtf(c));
  }
}

__global__ __launch_bounds__(256) void scan_phaseA(const int* __restrict__ counts,
    int* __restrict__ blksum, int N) {
  __shared__ int red[256];
  int base = blockIdx.x * SCAN_CH;
  int t = threadIdx.x;
  int s = 0;
  #pragma unroll
  for (int j = 0; j < 4; ++j) {
    int idx = base + t * 4 + j;
    if (idx < N) s += counts[idx];
  }
  red[t] = s;
  __syncthreads();
  for (int d = 128; d > 0; d >>= 1) {
    if (t < d) red[t] += red[t + d];
    __syncthreads();
  }
  if (t == 0) blksum[blockIdx.x] = red[0];
}

__global__ __launch_bounds__(1024) void scan_phaseB(int* __restrict__ blksum, int NB) {
  __shared__ int sa[1024], sb[1024];
  int t = threadIdx.x;
  int v = (t < NB) ? blksum[t] : 0;
  sa[t] = v;
  __syncthreads();
  int* a = sa; int* b = sb;
  for (int d = 1; d < 1024; d <<= 1) {
    int val = a[t] + ((t >= d) ? a[t - d] : 0);
    b[t] = val;
    __syncthreads();
    int* tmp = a; a = b; b = tmp;
  }
  if (t < NB) blksum[t] = a[t] - v;  // exclusive
}

__global__ __launch_bounds__(256) void scan_phaseC(const int* __restrict__ counts,
    const int* __restrict__ blksum, int* __restrict__ row_ptr, int* __restrict__ fillp, int N) {
  __shared__ int ra[256], rb[256];
  int base = blockIdx.x * SCAN_CH;
  int t = threadIdx.x;
  int v[4]; int s = 0;
  #pragma unroll
  for (int j = 0; j < 4; ++j) {
    int idx = base + t * 4 + j;
    v[j] = (idx < N) ? counts[idx] : 0;
    s += v[j];
  }
  ra[t] = s;
  __syncthreads();
  int* a = ra; int* b = rb;
  for (int d = 1; d < 256; d <<= 1) {
    int val = a[t] + ((t >= d) ? a[t - d] : 0);
    b[t] = val;
    __syncthreads();
    int* tmp = a; a = b; b = tmp;
  }
  int excl = a[t] - s + blksum[blockIdx.x];
  #pragma unroll
  for (int j = 0; j < 4; ++j) {
    int idx = base + t * 4 + j;
    if (idx < N) {
      row_ptr[idx] = excl;
      fillp[idx] = excl;
      excl += v[j];
      if (idx == N - 1) row_ptr[N] = excl;
    }
  }
}

// ---------------- degree-sorted permutation (descending: heavy blocks first) ----------------

__global__ __launch_bounds__(256) void keyhist_kernel(const int* __restrict__ counts,
    int* __restrict__ ghist, int N) {
  __shared__ int lh[256];
  int t = threadIdx.x;
  lh[t] = 0;
  __syncthreads();
  for (int n = blockIdx.x * 256 + t; n < N; n += gridDim.x * 256) {
    int k = 255 - min(counts[n], 255);
    atomicAdd(&lh[k], 1);
  }
  __syncthreads();
  if (lh[t]) atomicAdd(&ghist[t], lh[t]);
}

__global__ __launch_bounds__(256) void keyscan_kernel(const int* __restrict__ ghist,
    int* __restrict__ binwork) {
  __shared__ int a_[256], b_[256];
  int t = threadIdx.x;
  int v = ghist[t];
  a_[t] = v;
  __syncthreads();
  int* a = a_; int* b = b_;
  for (int d = 1; d < 256; d <<= 1) {
    int val = a[t] + ((t >= d) ? a[t - d] : 0);
    b[t] = val;
    __syncthreads();
    int* tmp = a; a = b; b = tmp;
  }
  binwork[t] = a[t] - v;  // exclusive
}

__global__ void scatter_perm_kernel(const int* __restrict__ counts,
    int* __restrict__ binwork, int* __restrict__ perm, int N) {
  int n = blockIdx.x * blockDim.x + threadIdx.x;
  if (n < N) {
    int k = 255 - min(counts[n], 255);
    int p = atomicAdd(&binwork[k], 1);
    perm[p] = n;
  }
}

// ---------------- one-time conversions ----------------

// gather table hs0 = dn * x[n]  (fp16)
__global__ void conv_x_kernel(const float* __restrict__ x, const float2* __restrict__ dnr,
    _Float16* __restrict__ hs, int total8) {
  int i = blockIdx.x * blockDim.x + threadIdx.x;
  if (i >= total8) return;
  int node = i >> 4;
  float dn = dnr[node].x;
  const float4* p = (const float4*)(x + (size_t)i * 8);
  float4 a = p[0], b = p[1];
  f16x8 v;
  v[0] = (_Float16)(dn * a.x); v[1] = (_Float16)(dn * a.y);
  v[2] = (_Float16)(dn * a.z); v[3] = (_Float16)(dn * a.w);
  v[4] = (_Float16)(dn * b.x); v[5] = (_Float16)(dn * b.y);
  v[6] = (_Float16)(dn * b.z); v[7] = (_Float16)(dn * b.w);
  *(f16x8*)(hs + (size_t)i * 8) = v;
}

// Wf layout: [L][kb(4)][nb(8)][lane(64)] of f16x8 (B fragment, K-slice 8)
__global__ void repack_w_kernel(const float* __restrict__ Ws, _Float16* __restrict__ Wf, int total) {
  int t = blockIdx.x * blockDim.x + threadIdx.x;
  if (t >= total) return;
  int lane = t & 63;
  int nb = (t >> 6) & 7;
  int kb = (t >> 9) & 3;
  int l = t >> 11;
  int col = nb * 16 + (lane & 15);
  int k0 = kb * 32 + (lane >> 4) * 8;
  const float* w = Ws + (size_t)l * D * D;
  f16x8 v;
  #pragma unroll
  for (int j = 0; j < 8; ++j) v[j] = (_Float16)w[(k0 + j) * D + col];
  *(f16x8*)(Wf + (size_t)t * 8) = v;
}

// ---------------- Fused conv ----------------
// conv_n = [dn*(sum_e hs[src_e] + hs[n])] @ W + b   (self-loop in gather)
// Nodes processed in degree-sorted perm order (block-level load balance).
// flags: 1=+init, 2=write init16, 4=relu, 8=+h (ownr*rdn), 16=write hs_out,
//        32=write out (fp32), 64=init source is fp32 x
__global__ __launch_bounds__(CONV_THREADS) void conv_fused_kernel(
    const _Float16* __restrict__ hs, const int* __restrict__ row_ptr,
    const int* __restrict__ csr_src, const float2* __restrict__ dnr,
    const int* __restrict__ perm, const f16x8* __restrict__ Wf,
    const float* __restrict__ bias, const float* __restrict__ init32,
    const _Float16* __restrict__ init16in, _Float16* __restrict__ init16out,
    float* __restrict__ out, _Float16* __restrict__ hs_out, int N, int flags) {
  __shared__ __align__(16) char smem[NPB * SC_STRIDE * 4];  // sA and sC alias
  _Float16* sA = (_Float16*)smem;
  float* sC = (float*)smem;
  int tid = threadIdx.x;
  int node0 = blockIdx.x * NPB;
  int g32 = tid >> 5;         // 0..15 group of 32 lanes
  int li = tid & 31;
  int c0 = li * 4;            // 4 features per lane

  int nsv[4];
  float2 dr[4];
  f16x4 ownr[4];

  // ---- gather: each 32-lane group handles 4 nodes sequentially ----
  #pragma unroll
  for (int k = 0; k < 4; ++k) {
    int lr = g32 + 16 * k;
    int idx = node0 + lr;
    int n = (idx < N) ? perm[idx] : -1;
    nsv[k] = n;
    f16x4 g = {};
    if (n >= 0) {
      float a0 = 0.f, a1 = 0.f, a2 = 0.f, a3 = 0.f;
      int beg = row_ptr[n], end = row_ptr[n + 1];
      int e = beg;
      for (; e + 8 <= end; e += 8) {
        int s0 = csr_src[e + 0], s1 = csr_src[e + 1];
        int s2 = csr_src[e + 2], s3 = csr_src[e + 3];
        int s4 = csr_src[e + 4], s5 = csr_src[e + 5];
        int s6 = csr_src[e + 6], s7 = csr_src[e + 7];
        f16x4 v0 = *(const f16x4*)&hs[(size_t)s0 * D + c0];
        f16x4 v1 = *(const f16x4*)&hs[(size_t)s1 * D + c0];
        f16x4 v2 = *(const f16x4*)&hs[(size_t)s2 * D + c0];
        f16x4 v3 = *(const f16x4*)&hs[(size_t)s3 * D + c0];
        f16x4 v4 = *(const f16x4*)&hs[(size_t)s4 * D + c0];
        f16x4 v5 = *(const f16x4*)&hs[(size_t)s5 * D + c0];
        f16x4 v6 = *(const f16x4*)&hs[(size_t)s6 * D + c0];
        f16x4 v7 = *(const f16x4*)&hs[(size_t)s7 * D + c0];
        a0 += (float)v0[0] + (float)v1[0] + (float)v2[0] + (float)v3[0]
            + (float)v4[0] + (float)v5[0] + (float)v6[0] + (float)v7[0];
        a1 += (float)v0[1] + (float)v1[1] + (float)v2[1] + (float)v3[1]
            + (float)v4[1] + (float)v5[1] + (float)v6[1] + (float)v7[1];
        a2 += (float)v0[2] + (float)v1[2] + (float)v2[2] + (float)v3[2]
            + (float)v4[2] + (float)v5[2] + (float)v6[2] + (float)v7[2];
        a3 += (float)v0[3] + (float)v1[3] + (float)v2[3] + (float)v3[3]
            + (float)v4[3] + (float)v5[3] + (float)v6[3] + (float)v7[3];
      }
      for (; e < end; ++e) {
        int s = csr_src[e];
        f16x4 v = *(const f16x4*)&hs[(size_t)s * D + c0];
        a0 += (float)v[0]; a1 += (float)v[1]; a2 += (float)v[2]; a3 += (float)v[3];
      }
      f16x4 own = *(const f16x4*)&hs[(size_t)n * D + c0];
      float2 d2 = dnr[n];
      dr[k] = d2;
      ownr[k] = own;
      g[0] = (_Float16)(d2.x * (a0 + (float)own[0]));
      g[1] = (_Float16)(d2.x * (a1 + (float)own[1]));
      g[2] = (_Float16)(d2.x * (a2 + (float)own[2]));
      g[3] = (_Float16)(d2.x * (a3 + (float)own[3]));
    }
    *(f16x4*)&sA[lr * SA_STRIDE + c0] = g;
  }

  // ---- B fragments: wave w owns 16-col block w ----
  int wave = tid >> 6, lane = tid & 63;
  f16x8 bf[4];
  #pragma unroll
  for (int kb = 0; kb < 4; ++kb)
    bf[kb] = Wf[(kb * 8 + wave) * 64 + lane];
  __syncthreads();

  // ---- MFMA: 64x128 A (4 row-tiles) x per-wave 16 cols ----
  f32x4 ca[4];
  #pragma unroll
  for (int rt = 0; rt < 4; ++rt) ca[rt] = (f32x4){0, 0, 0, 0};
  #pragma unroll
  for (int rt = 0; rt < 4; ++rt) {
    #pragma unroll
    for (int kb = 0; kb < 4; ++kb) {
      f16x8 a = *(const f16x8*)&sA[(rt * 16 + (lane & 15)) * SA_STRIDE + kb * 32 + (lane >> 4) * 8];
      ca[rt] = __builtin_amdgcn_mfma_f32_16x16x32_f16(a, bf[kb], ca[rt], 0, 0, 0);
    }
  }
  __syncthreads();   // all sA reads done before sC overwrites the same LDS

  // ---- stage C ----
  {
    int colb = wave * 16 + (lane & 15);
    int rowb = (lane >> 4) * 4;
    #pragma unroll
    for (int rt = 0; rt < 4; ++rt)
      #pragma unroll
      for (int r = 0; r < 4; ++r)
        sC[(rt * 16 + rowb + r) * SC_STRIDE + colb] = ca[rt][r];
  }
  __syncthreads();

  // ---- epilogue: 4 passes; each lane handles 4 features of one node ----
  float4 bv = *(const float4*)&bias[c0];
  #pragma unroll
  for (int k = 0; k < 4; ++k) {
    int n = nsv[k];
    if (n < 0) continue;
    int lr = g32 + 16 * k;
    float4 s0 = *(const float4*)&sC[lr * SC_STRIDE + c0];
    float v0 = s0.x + bv.x, v1 = s0.y + bv.y, v2 = s0.z + bv.z, v3 = s0.w + bv.w;
    size_t off = (size_t)n * D + c0;
    if (flags & 8) {     // h-add: h = hs_own * rdn (no global read)
      float rd = dr[k].y;
      v0 += (float)ownr[k][0] * rd; v1 += (float)ownr[k][1] * rd;
      v2 += (float)ownr[k][2] * rd; v3 += (float)ownr[k][3] * rd;
    }
    if (flags & 1) {
      if (flags & 64) {
        float4 iv = *(const float4*)&init32[off];
        v0 += iv.x; v1 += iv.y; v2 += iv.z; v3 += iv.w;
      } else {
        f16x4 iv = *(const f16x4*)&init16in[off];
        v0 += (float)iv[0]; v1 += (float)iv[1]; v2 += (float)iv[2]; v3 += (float)iv[3];
      }
    }
    if (flags & 2) {
      f16x4 o;
      o[0] = (_Float16)v0; o[1] = (_Float16)v1; o[2] = (_Float16)v2; o[3] = (_Float16)v3;
      *(f16x4*)&init16out[off] = o;
    }
    if (flags & 4) {
      v0 = fmaxf(v0, 0.f); v1 = fmaxf(v1, 0.f); v2 = fmaxf(v2, 0.f); v3 = fmaxf(v3, 0.f);
    }
    if (flags & 32) {
      *(float4*)&out[off] = make_float4(v0, v1, v2, v3);
    }
    if (flags & 16) {
      float dn = dr[k].x;
      f16x4 h;
      h[0] = (_Float16)(dn * v0); h[1] = (_Float16)(dn * v1);
      h[2] = (_Float16)(dn * v2); h[3] = (_Float16)(dn * v3);
      *(f16x4*)&hs_out[off] = h;
    }
  }
}

// ---------------- launch ----------------

extern "C" void kernel_launch(void* const* d_in, const int* in_sizes, int n_in,
                              void* d_out, int out_size, void* d_ws, size_t ws_size,
                              hipStream_t stream) {
  const float* x = (const float*)d_in[0];
  const int* ei = (const int*)d_in[1];
  const float* Ws = (const float*)d_in[2];
  const float* bs = (const float*)d_in[3];
  float* out = (float*)d_out;

  const int N = in_sizes[0] / D;
  const int E = in_sizes[1] / 2;
  const int L = in_sizes[2] / (D * D);
  const int* src = ei;
  const int* dst = ei + E;

  uintptr_t p = (uintptr_t)d_ws;
  auto alloc = [&](size_t bytes) {
    uintptr_t r = p;
    p = (r + bytes + 255) & ~(uintptr_t)255;
    return r;
  };
  float2*    dnr      = (float2*)alloc((size_t)N * 8);
  int*       counts   = (int*)  alloc((size_t)N * 4);
  int*       row_ptr  = (int*)  alloc((size_t)(N + 1) * 4);
  int*       fillp    = (int*)  alloc((size_t)N * 4);
  int*       blksum   = (int*)  alloc((size_t)1024 * 4);
  int*       ghist    = (int*)  alloc((size_t)256 * 4);
  int*       binwork  = (int*)  alloc((size_t)256 * 4);
  int*       perm     = (int*)  alloc((size_t)N * 4);
  int*       csr_src  = (int*)  alloc((size_t)E * 4);
  _Float16*  hs_a     = (_Float16*)alloc((size_t)N * D * 2);  // ping
  _Float16*  hs_b     = (_Float16*)alloc((size_t)N * D * 2);  // pong
  _Float16*  init16   = (_Float16*)alloc((size_t)N * D * 2);
  _Float16*  Wf       = (_Float16*)alloc((size_t)L * 4 * 8 * 64 * 8 * 2);

  const int NB = (N + SCAN_CH - 1) / SCAN_CH;

  hipMemsetAsync(counts, 0, (size_t)N * 4, stream);
  hipMemsetAsync(ghist, 0, 256 * 4, stream);
  hist_kernel<<<8 * 192, 256, 0, stream>>>(dst, counts, E, N);
  dis_kernel<<<(N + 255) / 256, 256, 0, stream>>>(counts, dnr, N);
  scan_phaseA<<<NB, 256, 0, stream>>>(counts, blksum, N);
  scan_phaseB<<<1, 1024, 0, stream>>>(blksum, NB);
  scan_phaseC<<<NB, 256, 0, stream>>>(counts, blksum, row_ptr, fillp, N);
  fill_kernel<<<8 * 192, 256, 0, stream>>>(src, dst, fillp, csr_src, E, N);
  keyhist_kernel<<<128, 256, 0, stream>>>(counts, ghist, N);
  keyscan_kernel<<<1, 256, 0, stream>>>(ghist, binwork);
  scatter_perm_kernel<<<(N + 255) / 256, 256, 0, stream>>>(counts, binwork, perm, N);
  conv_x_kernel<<<(N * 16 + 255) / 256, 256, 0, stream>>>(x, dnr, hs_a, N * 16);
  {
    int total = L * 2048;
    repack_w_kernel<<<(total + 255) / 256, 256, 0, stream>>>(Ws, Wf, total);
  }

  const int conv_grid = (N + NPB - 1) / NPB;
  _Float16* hsp[2] = {hs_a, hs_b};
  int cur = 0;

  for (int i = 0; i < L; ++i) {
    int flags;
    if (i == 0)          flags = 4 | 16;
    else if (i == L - 1) flags = 1 | 4 | 32;
    else                 flags = 1 | 2 | 4 | 16;
    if (i == 1)          flags |= 64;   // init source is fp32 x
    conv_fused_kernel<<<conv_grid, CONV_THREADS, 0, stream>>>(hsp[cur], row_ptr, csr_src,
        dnr, perm, (const f16x8*)(Wf + (size_t)i * 2048 * 8), bs + (size_t)i * D,
        x, init16, init16, out, hsp[cur ^ 1], N, flags);
    if (flags & 16) cur ^= 1;
    if (i < L - 1) {
      int j = (i == 0) ? (L - 1) : (i - 1);
      conv_fused_kernel<<<conv_grid, CONV_THREADS, 0, stream>>>(hsp[cur], row_ptr, csr_src,
          dnr, perm, (const f16x8*)(Wf + (size_t)j * 2048 * 8), bs + (size_t)j * D,
          x, init16, init16, out, hsp[cur ^ 1], N, 8 | 16);
      cur ^= 1;
    }
  }
}

// Round 10
// 1266.827 us; speedup vs baseline: 1.4965x; 1.4965x over previous
//
#include <hip/hip_runtime.h>

#define D 128
#define SCAN_CH 1024
#define SA_STRIDE 136   // fp16 units; 272B row
#define SC_STRIDE 132   // fp32 units; 528B row
#define NPB 64          // nodes per conv block
#define CONV_THREADS 512

typedef _Float16 f16x8 __attribute__((ext_vector_type(8)));
typedef _Float16 f16x4 __attribute__((ext_vector_type(4)));
typedef float f32x4 __attribute__((ext_vector_type(4)));

// ---------------- CSR build (XCD-affinity: blockIdx%8 owns dst-range) ----------------

__global__ void hist_kernel(const int* __restrict__ dst, int* __restrict__ counts,
                            int E, int N) {
  int range = blockIdx.x & 7;
  int lo = (int)(((long long)N * range) >> 3);
  int hi = (int)(((long long)N * (range + 1)) >> 3);
  int stride = (gridDim.x >> 3) * blockDim.x;
  for (int e = (blockIdx.x >> 3) * blockDim.x + threadIdx.x; e < E; e += stride) {
    int d = dst[e];
    if (d >= lo && d < hi) atomicAdd(&counts[d], 1);
  }
}

__global__ void fill_kernel(const int* __restrict__ src, const int* __restrict__ dst,
    int* __restrict__ fillp, int* __restrict__ csr_src, int E, int N) {
  int range = blockIdx.x & 7;
  int lo = (int)(((long long)N * range) >> 3);
  int hi = (int)(((long long)N * (range + 1)) >> 3);
  int stride = (gridDim.x >> 3) * blockDim.x;
  for (int e = (blockIdx.x >> 3) * blockDim.x + threadIdx.x; e < E; e += stride) {
    int d = dst[e];
    if (d >= lo && d < hi) {
      int s = src[e];
      int p = atomicAdd(&fillp[d], 1);
      csr_src[p] = s;
    }
  }
}

// dnr[n] = (dn = 1/sqrt(deg+1), rdn = sqrt(deg+1))
__global__ void dis_kernel(const int* __restrict__ counts, float2* __restrict__ dnr, int N) {
  int n = blockIdx.x * blockDim.x + threadIdx.x;
  if (n < N) {
    float c = (float)counts[n] + 1.0f;
    dnr[n] = make_float2(rsqrtf(c), sqrtf(c));
  }
}

__global__ __launch_bounds__(256) void scan_phaseA(const int* __restrict__ counts,
    int* __restrict__ blksum, int N) {
  __shared__ int red[256];
  int base = blockIdx.x * SCAN_CH;
  int t = threadIdx.x;
  int s = 0;
  #pragma unroll
  for (int j = 0; j < 4; ++j) {
    int idx = base + t * 4 + j;
    if (idx < N) s += counts[idx];
  }
  red[t] = s;
  __syncthreads();
  for (int d = 128; d > 0; d >>= 1) {
    if (t < d) red[t] += red[t + d];
    __syncthreads();
  }
  if (t == 0) blksum[blockIdx.x] = red[0];
}

__global__ __launch_bounds__(1024) void scan_phaseB(int* __restrict__ blksum, int NB) {
  __shared__ int sa[1024], sb[1024];
  int t = threadIdx.x;
  int v = (t < NB) ? blksum[t] : 0;
  sa[t] = v;
  __syncthreads();
  int* a = sa; int* b = sb;
  for (int d = 1; d < 1024; d <<= 1) {
    int val = a[t] + ((t >= d) ? a[t - d] : 0);
    b[t] = val;
    __syncthreads();
    int* tmp = a; a = b; b = tmp;
  }
  if (t < NB) blksum[t] = a[t] - v;  // exclusive
}

__global__ __launch_bounds__(256) void scan_phaseC(const int* __restrict__ counts,
    const int* __restrict__ blksum, int* __restrict__ row_ptr, int* __restrict__ fillp, int N) {
  __shared__ int ra[256], rb[256];
  int base = blockIdx.x * SCAN_CH;
  int t = threadIdx.x;
  int v[4]; int s = 0;
  #pragma unroll
  for (int j = 0; j < 4; ++j) {
    int idx = base + t * 4 + j;
    v[j] = (idx < N) ? counts[idx] : 0;
    s += v[j];
  }
  ra[t] = s;
  __syncthreads();
  int* a = ra; int* b = rb;
  for (int d = 1; d < 256; d <<= 1) {
    int val = a[t] + ((t >= d) ? a[t - d] : 0);
    b[t] = val;
    __syncthreads();
    int* tmp = a; a = b; b = tmp;
  }
  int excl = a[t] - s + blksum[blockIdx.x];
  #pragma unroll
  for (int j = 0; j < 4; ++j) {
    int idx = base + t * 4 + j;
    if (idx < N) {
      row_ptr[idx] = excl;
      fillp[idx] = excl;
      excl += v[j];
      if (idx == N - 1) row_ptr[N] = excl;
    }
  }
}

// ---------------- one-time conversions ----------------

// gather table hs0 = dn * x[n]  (fp16)
__global__ void conv_x_kernel(const float* __restrict__ x, const float2* __restrict__ dnr,
    _Float16* __restrict__ hs, int total8) {
  int i = blockIdx.x * blockDim.x + threadIdx.x;
  if (i >= total8) return;
  int node = i >> 4;
  float dn = dnr[node].x;
  const float4* p = (const float4*)(x + (size_t)i * 8);
  float4 a = p[0], b = p[1];
  f16x8 v;
  v[0] = (_Float16)(dn * a.x); v[1] = (_Float16)(dn * a.y);
  v[2] = (_Float16)(dn * a.z); v[3] = (_Float16)(dn * a.w);
  v[4] = (_Float16)(dn * b.x); v[5] = (_Float16)(dn * b.y);
  v[6] = (_Float16)(dn * b.z); v[7] = (_Float16)(dn * b.w);
  *(f16x8*)(hs + (size_t)i * 8) = v;
}

// Wf layout: [L][kb(4)][nb(8)][lane(64)] of f16x8 (B fragment, K-slice 8)
__global__ void repack_w_kernel(const float* __restrict__ Ws, _Float16* __restrict__ Wf, int total) {
  int t = blockIdx.x * blockDim.x + threadIdx.x;
  if (t >= total) return;
  int lane = t & 63;
  int nb = (t >> 6) & 7;
  int kb = (t >> 9) & 3;
  int l = t >> 11;
  int col = nb * 16 + (lane & 15);
  int k0 = kb * 32 + (lane >> 4) * 8;
  const float* w = Ws + (size_t)l * D * D;
  f16x8 v;
  #pragma unroll
  for (int j = 0; j < 8; ++j) v[j] = (_Float16)w[(k0 + j) * D + col];
  *(f16x8*)(Wf + (size_t)t * 8) = v;
}

// ---------------- Fused conv ----------------
// conv_n = [dn*(sum_e hs[src_e] + hs[n])] @ W + b   (self-loop in gather)
// Running h never round-trips through fp32 global: h[n] = hs[n]*rdn[n].
// flags: 1=+init, 2=write init16out, 4=relu, 8=+h (ownr*rdn), 16=write hs_out,
//        32=write out (fp32 final), 64=init source is fp32 x
__global__ __launch_bounds__(CONV_THREADS) void conv_fused_kernel(
    const _Float16* __restrict__ hs, const int* __restrict__ row_ptr,
    const int* __restrict__ csr_src, const float2* __restrict__ dnr,
    const f16x8* __restrict__ Wf, const float* __restrict__ bias,
    const float* __restrict__ init32, const _Float16* __restrict__ init16in,
    _Float16* __restrict__ init16out, float* __restrict__ out,
    _Float16* __restrict__ hs_out, int N, int flags) {
  __shared__ __align__(16) char smem[NPB * SC_STRIDE * 4];  // sA and sC alias
  _Float16* sA = (_Float16*)smem;
  float* sC = (float*)smem;
  int tid = threadIdx.x;
  int node0 = blockIdx.x * NPB;
  int ng = tid >> 4;          // 0..31 group of 16 lanes
  int li = tid & 15;
  int c0 = li * 8;

  float2 dr[2];
  f16x8 ownr[2];

  // ---- gather: each 16-lane group handles 2 nodes sequentially ----
  #pragma unroll
  for (int k = 0; k < 2; ++k) {
    int lr = ng + 32 * k;
    int n = node0 + lr;
    f16x8 g = {};
    if (n < N) {
      float acc[8];
      #pragma unroll
      for (int j = 0; j < 8; ++j) acc[j] = 0.f;
      int beg = row_ptr[n], end = row_ptr[n + 1];
      #pragma unroll 4
      for (int e = beg; e < end; ++e) {
        int s = csr_src[e];
        f16x8 v = *(const f16x8*)&hs[(size_t)s * D + c0];
        #pragma unroll
        for (int j = 0; j < 8; ++j) acc[j] += (float)v[j];
      }
      f16x8 own = *(const f16x8*)&hs[(size_t)n * D + c0];
      float2 d2 = dnr[n];
      dr[k] = d2;
      ownr[k] = own;
      #pragma unroll
      for (int j = 0; j < 8; ++j) g[j] = (_Float16)(d2.x * (acc[j] + (float)own[j]));
    }
    *(f16x8*)&sA[lr * SA_STRIDE + c0] = g;
  }

  // ---- B fragments: wave w owns 16-col block w ----
  int wave = tid >> 6, lane = tid & 63;
  f16x8 bf[4];
  #pragma unroll
  for (int kb = 0; kb < 4; ++kb)
    bf[kb] = Wf[(kb * 8 + wave) * 64 + lane];
  __syncthreads();

  // ---- MFMA: 64x128 A (4 row-tiles) x per-wave 16 cols ----
  f32x4 ca[4];
  #pragma unroll
  for (int rt = 0; rt < 4; ++rt) ca[rt] = (f32x4){0, 0, 0, 0};
  #pragma unroll
  for (int rt = 0; rt < 4; ++rt) {
    #pragma unroll
    for (int kb = 0; kb < 4; ++kb) {
      f16x8 a = *(const f16x8*)&sA[(rt * 16 + (lane & 15)) * SA_STRIDE + kb * 32 + (lane >> 4) * 8];
      ca[rt] = __builtin_amdgcn_mfma_f32_16x16x32_f16(a, bf[kb], ca[rt], 0, 0, 0);
    }
  }
  __syncthreads();   // all sA reads done before sC overwrites the same LDS

  // ---- stage C ----
  {
    int colb = wave * 16 + (lane & 15);
    int rowb = (lane >> 4) * 4;
    #pragma unroll
    for (int rt = 0; rt < 4; ++rt)
      #pragma unroll
      for (int r = 0; r < 4; ++r)
        sC[(rt * 16 + rowb + r) * SC_STRIDE + colb] = ca[rt][r];
  }
  __syncthreads();

  // ---- epilogue: 2 passes of 32 nodes; thread handles 8 features ----
  float4 b0 = *(const float4*)&bias[c0];
  float4 b1 = *(const float4*)&bias[c0 + 4];
  #pragma unroll
  for (int k = 0; k < 2; ++k) {
    int lr = ng + 32 * k;
    int n = node0 + lr;
    if (n >= N) continue;
    float v[8];
    float4 s0 = *(const float4*)&sC[lr * SC_STRIDE + c0];
    float4 s1 = *(const float4*)&sC[lr * SC_STRIDE + c0 + 4];
    v[0] = s0.x + b0.x; v[1] = s0.y + b0.y; v[2] = s0.z + b0.z; v[3] = s0.w + b0.w;
    v[4] = s1.x + b1.x; v[5] = s1.y + b1.y; v[6] = s1.z + b1.z; v[7] = s1.w + b1.w;
    size_t off = (size_t)n * D + c0;
    if (flags & 8) {     // h-add: h = hs_own * rdn (no global read)
      float rd = dr[k].y;
      #pragma unroll
      for (int j = 0; j < 8; ++j) v[j] += (float)ownr[k][j] * rd;
    }
    if (flags & 1) {
      if (flags & 64) {
        float4 i0 = *(const float4*)&init32[off];
        float4 i1 = *(const float4*)&init32[off + 4];
        v[0] += i0.x; v[1] += i0.y; v[2] += i0.z; v[3] += i0.w;
        v[4] += i1.x; v[5] += i1.y; v[6] += i1.z; v[7] += i1.w;
      } else {
        f16x8 iv = *(const f16x8*)&init16in[off];
        #pragma unroll
        for (int j = 0; j < 8; ++j) v[j] += (float)iv[j];
      }
    }
    if (flags & 2) {
      f16x8 o;
      #pragma unroll
      for (int j = 0; j < 8; ++j) o[j] = (_Float16)v[j];
      *(f16x8*)&init16out[off] = o;
    }
    if (flags & 4) {
      #pragma unroll
      for (int j = 0; j < 8; ++j) v[j] = fmaxf(v[j], 0.f);
    }
    if (flags & 32) {
      *(float4*)&out[off]     = make_float4(v[0], v[1], v[2], v[3]);
      *(float4*)&out[off + 4] = make_float4(v[4], v[5], v[6], v[7]);
    }
    if (flags & 16) {
      float dn = dr[k].x;
      f16x8 h8;
      #pragma unroll
      for (int j = 0; j < 8; ++j) h8[j] = (_Float16)(dn * v[j]);
      *(f16x8*)&hs_out[off] = h8;
    }
  }
}

// ---------------- launch ----------------

extern "C" void kernel_launch(void* const* d_in, const int* in_sizes, int n_in,
                              void* d_out, int out_size, void* d_ws, size_t ws_size,
                              hipStream_t stream) {
  const float* x = (const float*)d_in[0];
  const int* ei = (const int*)d_in[1];
  const float* Ws = (const float*)d_in[2];
  const float* bs = (const float*)d_in[3];
  float* out = (float*)d_out;

  const int N = in_sizes[0] / D;
  const int E = in_sizes[1] / 2;
  const int L = in_sizes[2] / (D * D);
  const int* src = ei;
  const int* dst = ei + E;

  uintptr_t p = (uintptr_t)d_ws;
  auto alloc = [&](size_t bytes) {
    uintptr_t r = p;
    p = (r + bytes + 255) & ~(uintptr_t)255;
    return r;
  };
  float2*    dnr      = (float2*)alloc((size_t)N * 8);
  int*       counts   = (int*)  alloc((size_t)N * 4);
  int*       row_ptr  = (int*)  alloc((size_t)(N + 1) * 4);
  int*       fillp    = (int*)  alloc((size_t)N * 4);
  int*       blksum   = (int*)  alloc((size_t)1024 * 4);
  int*       csr_src  = (int*)  alloc((size_t)E * 4);
  _Float16*  hs_a     = (_Float16*)alloc((size_t)N * D * 2);  // ping
  _Float16*  hs_b     = (_Float16*)alloc((size_t)N * D * 2);  // pong
  _Float16*  init16   = (_Float16*)alloc((size_t)N * D * 2);
  _Float16*  Wf       = (_Float16*)alloc((size_t)L * 4 * 8 * 64 * 8 * 2);

  const int NB = (N + SCAN_CH - 1) / SCAN_CH;

  hipMemsetAsync(counts, 0, (size_t)N * 4, stream);
  hist_kernel<<<8 * 192, 256, 0, stream>>>(dst, counts, E, N);
  dis_kernel<<<(N + 255) / 256, 256, 0, stream>>>(counts, dnr, N);
  scan_phaseA<<<NB, 256, 0, stream>>>(counts, blksum, N);
  scan_phaseB<<<1, 1024, 0, stream>>>(blksum, NB);
  scan_phaseC<<<NB, 256, 0, stream>>>(counts, blksum, row_ptr, fillp, N);
  fill_kernel<<<8 * 192, 256, 0, stream>>>(src, dst, fillp, csr_src, E, N);
  conv_x_kernel<<<(N * 16 + 255) / 256, 256, 0, stream>>>(x, dnr, hs_a, N * 16);
  {
    int total = L * 2048;
    repack_w_kernel<<<(total + 255) / 256, 256, 0, stream>>>(Ws, Wf, total);
  }

  const int conv_grid = (N + NPB - 1) / NPB;
  _Float16* hsp[2] = {hs_a, hs_b};
  int cur = 0;

  for (int i = 0; i < L; ++i) {
    int flags;
    if (i == 0)          flags = 4 | 16;
    else if (i == L - 1) flags = 1 | 4 | 32;
    else                 flags = 1 | 2 | 4 | 16;
    if (i == 1)          flags |= 64;   // init source is fp32 x
    conv_fused_kernel<<<conv_grid, CONV_THREADS, 0, stream>>>(hsp[cur], row_ptr, csr_src,
        dnr, (const f16x8*)(Wf + (size_t)i * 2048 * 8), bs + (size_t)i * D,
        x, init16, init16, out, hsp[cur ^ 1], N, flags);
    if (flags & 16) cur ^= 1;
    if (i < L - 1) {
      int j = (i == 0) ? (L - 1) : (i - 1);
      conv_fused_kernel<<<conv_grid, CONV_THREADS, 0, stream>>>(hsp[cur], row_ptr, csr_src,
          dnr, (const f16x8*)(Wf + (size_t)j * 2048 * 8), bs + (size_t)j * D,
          x, init16, init16, out, hsp[cur ^ 1], N, 8 | 16);
      cur ^= 1;
    }
  }
}

// Round 11
// 1261.941 us; speedup vs baseline: 1.5023x; 1.0039x over previous
//
#include <hip/hip_runtime.h>

#define D 128
#define SCAN_CH 1024
#define SA_STRIDE 136   // fp16 units; 272B row
#define SC_STRIDE 132   // fp32 units; 528B row
#define NPB 64          // nodes per conv block
#define CONV_THREADS 512

typedef _Float16 f16x8 __attribute__((ext_vector_type(8)));
typedef float f32x4 __attribute__((ext_vector_type(4)));

// ---------------- CSR build (XCD-affinity: blockIdx%8 owns dst-range) ----------------

__global__ void hist_kernel(const int* __restrict__ dst, int* __restrict__ counts,
                            int E, int N) {
  int range = blockIdx.x & 7;
  int lo = (int)(((long long)N * range) >> 3);
  int hi = (int)(((long long)N * (range + 1)) >> 3);
  int stride = (gridDim.x >> 3) * blockDim.x;
  for (int e = (blockIdx.x >> 3) * blockDim.x + threadIdx.x; e < E; e += stride) {
    int d = dst[e];
    if (d >= lo && d < hi) atomicAdd(&counts[d], 1);
  }
}

__global__ void fill_kernel(const int* __restrict__ src, const int* __restrict__ dst,
    int* __restrict__ fillp, int* __restrict__ csr_src, int E, int N) {
  int range = blockIdx.x & 7;
  int lo = (int)(((long long)N * range) >> 3);
  int hi = (int)(((long long)N * (range + 1)) >> 3);
  int stride = (gridDim.x >> 3) * blockDim.x;
  for (int e = (blockIdx.x >> 3) * blockDim.x + threadIdx.x; e < E; e += stride) {
    int d = dst[e];
    if (d >= lo && d < hi) {
      int s = src[e];
      int p = atomicAdd(&fillp[d], 1);
      csr_src[p] = s;
    }
  }
}

// dnr[n] = (dn = 1/sqrt(deg+1), rdn = sqrt(deg+1))
__global__ void dis_kernel(const int* __restrict__ counts, float2* __restrict__ dnr, int N) {
  int n = blockIdx.x * blockDim.x + threadIdx.x;
  if (n < N) {
    float c = (float)counts[n] + 1.0f;
    dnr[n] = make_float2(rsqrtf(c), sqrtf(c));
  }
}

__global__ __launch_bounds__(256) void scan_phaseA(const int* __restrict__ counts,
    int* __restrict__ blksum, int N) {
  __shared__ int red[256];
  int base = blockIdx.x * SCAN_CH;
  int t = threadIdx.x;
  int s = 0;
  #pragma unroll
  for (int j = 0; j < 4; ++j) {
    int idx = base + t * 4 + j;
    if (idx < N) s += counts[idx];
  }
  red[t] = s;
  __syncthreads();
  for (int d = 128; d > 0; d >>= 1) {
    if (t < d) red[t] += red[t + d];
    __syncthreads();
  }
  if (t == 0) blksum[blockIdx.x] = red[0];
}

__global__ __launch_bounds__(1024) void scan_phaseB(int* __restrict__ blksum, int NB) {
  __shared__ int sa[1024], sb[1024];
  int t = threadIdx.x;
  int v = (t < NB) ? blksum[t] : 0;
  sa[t] = v;
  __syncthreads();
  int* a = sa; int* b = sb;
  for (int d = 1; d < 1024; d <<= 1) {
    int val = a[t] + ((t >= d) ? a[t - d] : 0);
    b[t] = val;
    __syncthreads();
    int* tmp = a; a = b; b = tmp;
  }
  if (t < NB) blksum[t] = a[t] - v;  // exclusive
}

__global__ __launch_bounds__(256) void scan_phaseC(const int* __restrict__ counts,
    const int* __restrict__ blksum, int* __restrict__ row_ptr, int* __restrict__ fillp, int N) {
  __shared__ int ra[256], rb[256];
  int base = blockIdx.x * SCAN_CH;
  int t = threadIdx.x;
  int v[4]; int s = 0;
  #pragma unroll
  for (int j = 0; j < 4; ++j) {
    int idx = base + t * 4 + j;
    v[j] = (idx < N) ? counts[idx] : 0;
    s += v[j];
  }
  ra[t] = s;
  __syncthreads();
  int* a = ra; int* b = rb;
  for (int d = 1; d < 256; d <<= 1) {
    int val = a[t] + ((t >= d) ? a[t - d] : 0);
    b[t] = val;
    __syncthreads();
    int* tmp = a; a = b; b = tmp;
  }
  int excl = a[t] - s + blksum[blockIdx.x];
  #pragma unroll
  for (int j = 0; j < 4; ++j) {
    int idx = base + t * 4 + j;
    if (idx < N) {
      row_ptr[idx] = excl;
      fillp[idx] = excl;
      excl += v[j];
      if (idx == N - 1) row_ptr[N] = excl;
    }
  }
}

// ---------------- degree-sorted permutation (descending; cheap scatter) ----------------

__global__ __launch_bounds__(256) void keyhist_kernel(const int* __restrict__ counts,
    int* __restrict__ ghist, int N) {
  __shared__ int lh[256];
  int t = threadIdx.x;
  lh[t] = 0;
  __syncthreads();
  for (int n = blockIdx.x * 256 + t; n < N; n += gridDim.x * 256) {
    int k = 255 - min(counts[n], 255);
    atomicAdd(&lh[k], 1);
  }
  __syncthreads();
  if (lh[t]) atomicAdd(&ghist[t], lh[t]);
}

__global__ __launch_bounds__(256) void keyscan_kernel(const int* __restrict__ ghist,
    int* __restrict__ binwork) {
  __shared__ int a_[256], b_[256];
  int t = threadIdx.x;
  int v = ghist[t];
  a_[t] = v;
  __syncthreads();
  int* a = a_; int* b = b_;
  for (int d = 1; d < 256; d <<= 1) {
    int val = a[t] + ((t >= d) ? a[t - d] : 0);
    b[t] = val;
    __syncthreads();
    int* tmp = a; a = b; b = tmp;
  }
  binwork[t] = a[t] - v;  // exclusive
}

// block-aggregated scatter: one global atomic per (block,bin), LDS-atomic ranks
__global__ __launch_bounds__(256) void scatter_perm_kernel(const int* __restrict__ counts,
    int* __restrict__ binwork, int* __restrict__ perm, int N) {
  __shared__ int cnt[256];
  __shared__ int base[256];
  int t = threadIdx.x;
  cnt[t] = 0;
  __syncthreads();
  int n = blockIdx.x * 256 + t;
  int k = -1;
  if (n < N) {
    k = 255 - min(counts[n], 255);
    atomicAdd(&cnt[k], 1);
  }
  __syncthreads();
  int c = cnt[t];
  if (c) base[t] = atomicAdd(&binwork[t], c);
  cnt[t] = 0;
  __syncthreads();
  if (k >= 0) {
    int r = atomicAdd(&cnt[k], 1);
    perm[base[k] + r] = n;
  }
}

// ---------------- one-time conversions ----------------

// gather table hs0 = dn * x[n]  (fp16)
__global__ void conv_x_kernel(const float* __restrict__ x, const float2* __restrict__ dnr,
    _Float16* __restrict__ hs, int total8) {
  int i = blockIdx.x * blockDim.x + threadIdx.x;
  if (i >= total8) return;
  int node = i >> 4;
  float dn = dnr[node].x;
  const float4* p = (const float4*)(x + (size_t)i * 8);
  float4 a = p[0], b = p[1];
  f16x8 v;
  v[0] = (_Float16)(dn * a.x); v[1] = (_Float16)(dn * a.y);
  v[2] = (_Float16)(dn * a.z); v[3] = (_Float16)(dn * a.w);
  v[4] = (_Float16)(dn * b.x); v[5] = (_Float16)(dn * b.y);
  v[6] = (_Float16)(dn * b.z); v[7] = (_Float16)(dn * b.w);
  *(f16x8*)(hs + (size_t)i * 8) = v;
}

// Wf layout: [L][kb(4)][nb(8)][lane(64)] of f16x8 (B fragment, K-slice 8)
__global__ void repack_w_kernel(const float* __restrict__ Ws, _Float16* __restrict__ Wf, int total) {
  int t = blockIdx.x * blockDim.x + threadIdx.x;
  if (t >= total) return;
  int lane = t & 63;
  int nb = (t >> 6) & 7;
  int kb = (t >> 9) & 3;
  int l = t >> 11;
  int col = nb * 16 + (lane & 15);
  int k0 = kb * 32 + (lane >> 4) * 8;
  const float* w = Ws + (size_t)l * D * D;
  f16x8 v;
  #pragma unroll
  for (int j = 0; j < 8; ++j) v[j] = (_Float16)w[(k0 + j) * D + col];
  *(f16x8*)(Wf + (size_t)t * 8) = v;
}

// ---------------- Fused conv ----------------
// conv_n = [dn*(sum_e hs[src_e] + hs[n])] @ W + b   (self-loop in gather)
// Nodes processed in degree-sorted perm order (equal-degree blocks, heavy first).
// flags: 1=+init, 2=write init16out, 4=relu, 8=+h (ownr*rdn), 16=write hs_out,
//        32=write out (fp32 final), 64=init source is fp32 x
__global__ __launch_bounds__(CONV_THREADS) void conv_fused_kernel(
    const _Float16* __restrict__ hs, const int* __restrict__ row_ptr,
    const int* __restrict__ csr_src, const float2* __restrict__ dnr,
    const int* __restrict__ perm, const f16x8* __restrict__ Wf,
    const float* __restrict__ bias, const float* __restrict__ init32,
    const _Float16* __restrict__ init16in, _Float16* __restrict__ init16out,
    float* __restrict__ out, _Float16* __restrict__ hs_out, int N, int flags) {
  __shared__ __align__(16) char smem[NPB * SC_STRIDE * 4];  // sA and sC alias
  _Float16* sA = (_Float16*)smem;
  float* sC = (float*)smem;
  int tid = threadIdx.x;
  int node0 = blockIdx.x * NPB;
  int ng = tid >> 4;          // 0..31 group of 16 lanes
  int li = tid & 15;
  int c0 = li * 8;
  int wave = tid >> 6, lane = tid & 63;

  // ---- B fragments first: in flight under the gather ----
  f16x8 bf[4];
  #pragma unroll
  for (int kb = 0; kb < 4; ++kb)
    bf[kb] = Wf[(kb * 8 + wave) * 64 + lane];

  float2 dr[2];
  f16x8 ownr[2];
  int nv[2];

  // ---- gather: each 16-lane group handles 2 nodes sequentially ----
  #pragma unroll
  for (int k = 0; k < 2; ++k) {
    int lr = ng + 32 * k;
    int idx = node0 + lr;
    int n = (idx < N) ? perm[idx] : -1;
    nv[k] = n;
    f16x8 g = {};
    if (n >= 0) {
      float acc[8];
      #pragma unroll
      for (int j = 0; j < 8; ++j) acc[j] = 0.f;
      int beg = row_ptr[n], end = row_ptr[n + 1];
      #pragma unroll 4
      for (int e = beg; e < end; ++e) {
        int s = csr_src[e];
        f16x8 v = *(const f16x8*)&hs[(size_t)s * D + c0];
        #pragma unroll
        for (int j = 0; j < 8; ++j) acc[j] += (float)v[j];
      }
      f16x8 own = *(const f16x8*)&hs[(size_t)n * D + c0];
      float2 d2 = dnr[n];
      dr[k] = d2;
      ownr[k] = own;
      #pragma unroll
      for (int j = 0; j < 8; ++j) g[j] = (_Float16)(d2.x * (acc[j] + (float)own[j]));
    }
    *(f16x8*)&sA[lr * SA_STRIDE + c0] = g;
  }
  __syncthreads();

  // ---- MFMA: 64x128 A (4 row-tiles) x per-wave 16 cols ----
  f32x4 ca[4];
  #pragma unroll
  for (int rt = 0; rt < 4; ++rt) ca[rt] = (f32x4){0, 0, 0, 0};
  #pragma unroll
  for (int rt = 0; rt < 4; ++rt) {
    #pragma unroll
    for (int kb = 0; kb < 4; ++kb) {
      f16x8 a = *(const f16x8*)&sA[(rt * 16 + (lane & 15)) * SA_STRIDE + kb * 32 + (lane >> 4) * 8];
      ca[rt] = __builtin_amdgcn_mfma_f32_16x16x32_f16(a, bf[kb], ca[rt], 0, 0, 0);
    }
  }
  __syncthreads();   // all sA reads done before sC overwrites the same LDS

  // ---- stage C ----
  {
    int colb = wave * 16 + (lane & 15);
    int rowb = (lane >> 4) * 4;
    #pragma unroll
    for (int rt = 0; rt < 4; ++rt)
      #pragma unroll
      for (int r = 0; r < 4; ++r)
        sC[(rt * 16 + rowb + r) * SC_STRIDE + colb] = ca[rt][r];
  }
  __syncthreads();

  // ---- epilogue: 2 passes of 32 nodes; thread handles 8 features ----
  float4 b0 = *(const float4*)&bias[c0];
  float4 b1 = *(const float4*)&bias[c0 + 4];
  #pragma unroll
  for (int k = 0; k < 2; ++k) {
    int lr = ng + 32 * k;
    int n = nv[k];
    if (n < 0) continue;
    float v[8];
    float4 s0 = *(const float4*)&sC[lr * SC_STRIDE + c0];
    float4 s1 = *(const float4*)&sC[lr * SC_STRIDE + c0 + 4];
    v[0] = s0.x + b0.x; v[1] = s0.y + b0.y; v[2] = s0.z + b0.z; v[3] = s0.w + b0.w;
    v[4] = s1.x + b1.x; v[5] = s1.y + b1.y; v[6] = s1.z + b1.z; v[7] = s1.w + b1.w;
    size_t off = (size_t)n * D + c0;
    if (flags & 8) {     // h-add: h = hs_own * rdn (no global read)
      float rd = dr[k].y;
      #pragma unroll
      for (int j = 0; j < 8; ++j) v[j] += (float)ownr[k][j] * rd;
    }
    if (flags & 1) {
      if (flags & 64) {
        float4 i0 = *(const float4*)&init32[off];
        float4 i1 = *(const float4*)&init32[off + 4];
        v[0] += i0.x; v[1] += i0.y; v[2] += i0.z; v[3] += i0.w;
        v[4] += i1.x; v[5] += i1.y; v[6] += i1.z; v[7] += i1.w;
      } else {
        f16x8 iv = *(const f16x8*)&init16in[off];
        #pragma unroll
        for (int j = 0; j < 8; ++j) v[j] += (float)iv[j];
      }
    }
    if (flags & 2) {
      f16x8 o;
      #pragma unroll
      for (int j = 0; j < 8; ++j) o[j] = (_Float16)v[j];
      *(f16x8*)&init16out[off] = o;
    }
    if (flags & 4) {
      #pragma unroll
      for (int j = 0; j < 8; ++j) v[j] = fmaxf(v[j], 0.f);
    }
    if (flags & 32) {
      *(float4*)&out[off]     = make_float4(v[0], v[1], v[2], v[3]);
      *(float4*)&out[off + 4] = make_float4(v[4], v[5], v[6], v[7]);
    }
    if (flags & 16) {
      float dn = dr[k].x;
      f16x8 h8;
      #pragma unroll
      for (int j = 0; j < 8; ++j) h8[j] = (_Float16)(dn * v[j]);
      *(f16x8*)&hs_out[off] = h8;
    }
  }
}

// ---------------- launch ----------------

extern "C" void kernel_launch(void* const* d_in, const int* in_sizes, int n_in,
                              void* d_out, int out_size, void* d_ws, size_t ws_size,
                              hipStream_t stream) {
  const float* x = (const float*)d_in[0];
  const int* ei = (const int*)d_in[1];
  const float* Ws = (const float*)d_in[2];
  const float* bs = (const float*)d_in[3];
  float* out = (float*)d_out;

  const int N = in_sizes[0] / D;
  const int E = in_sizes[1] / 2;
  const int L = in_sizes[2] / (D * D);
  const int* src = ei;
  const int* dst = ei + E;

  uintptr_t p = (uintptr_t)d_ws;
  auto alloc = [&](size_t bytes) {
    uintptr_t r = p;
    p = (r + bytes + 255) & ~(uintptr_t)255;
    return r;
  };
  float2*    dnr      = (float2*)alloc((size_t)N * 8);
  int*       counts   = (int*)  alloc((size_t)N * 4);
  int*       row_ptr  = (int*)  alloc((size_t)(N + 1) * 4);
  int*       fillp    = (int*)  alloc((size_t)N * 4);
  int*       blksum   = (int*)  alloc((size_t)1024 * 4);
  int*       ghist    = (int*)  alloc((size_t)256 * 4);
  int*       binwork  = (int*)  alloc((size_t)256 * 4);
  int*       perm     = (int*)  alloc((size_t)N * 4);
  int*       csr_src  = (int*)  alloc((size_t)E * 4);
  _Float16*  hs_a     = (_Float16*)alloc((size_t)N * D * 2);  // ping
  _Float16*  hs_b     = (_Float16*)alloc((size_t)N * D * 2);  // pong
  _Float16*  init16   = (_Float16*)alloc((size_t)N * D * 2);
  _Float16*  Wf       = (_Float16*)alloc((size_t)L * 4 * 8 * 64 * 8 * 2);

  const int NB = (N + SCAN_CH - 1) / SCAN_CH;

  hipMemsetAsync(counts, 0, (size_t)N * 4, stream);
  hipMemsetAsync(ghist, 0, 256 * 4, stream);
  hist_kernel<<<8 * 192, 256, 0, stream>>>(dst, counts, E, N);
  dis_kernel<<<(N + 255) / 256, 256, 0, stream>>>(counts, dnr, N);
  scan_phaseA<<<NB, 256, 0, stream>>>(counts, blksum, N);
  scan_phaseB<<<1, 1024, 0, stream>>>(blksum, NB);
  scan_phaseC<<<NB, 256, 0, stream>>>(counts, blksum, row_ptr, fillp, N);
  fill_kernel<<<8 * 192, 256, 0, stream>>>(src, dst, fillp, csr_src, E, N);
  keyhist_kernel<<<128, 256, 0, stream>>>(counts, ghist, N);
  keyscan_kernel<<<1, 256, 0, stream>>>(ghist, binwork);
  scatter_perm_kernel<<<(N + 255) / 256, 256, 0, stream>>>(counts, binwork, perm, N);
  conv_x_kernel<<<(N * 16 + 255) / 256, 256, 0, stream>>>(x, dnr, hs_a, N * 16);
  {
    int total = L * 2048;
    repack_w_kernel<<<(total + 255) / 256, 256, 0, stream>>>(Ws, Wf, total);
  }

  const int conv_grid = (N + NPB - 1) / NPB;
  _Float16* hsp[2] = {hs_a, hs_b};
  int cur = 0;

  for (int i = 0; i < L; ++i) {
    int flags;
    if (i == 0)          flags = 4 | 16;
    else if (i == L - 1) flags = 1 | 4 | 32;
    else                 flags = 1 | 2 | 4 | 16;
    if (i == 1)          flags |= 64;   // init source is fp32 x
    conv_fused_kernel<<<conv_grid, CONV_THREADS, 0, stream>>>(hsp[cur], row_ptr, csr_src,
        dnr, perm, (const f16x8*)(Wf + (size_t)i * 2048 * 8), bs + (size_t)i * D,
        x, init16, init16, out, hsp[cur ^ 1], N, flags);
    if (flags & 16) cur ^= 1;
    if (i < L - 1) {
      int j = (i == 0) ? (L - 1) : (i - 1);
      conv_fused_kernel<<<conv_grid, CONV_THREADS, 0, stream>>>(hsp[cur], row_ptr, csr_src,
          dnr, perm, (const f16x8*)(Wf + (size_t)j * 2048 * 8), bs + (size_t)j * D,
          x, init16, init16, out, hsp[cur ^ 1], N, 8 | 16);
      cur ^= 1;
    }
  }
}